// Round 5
// baseline (325.037 us; speedup 1.0000x reference)
//
#include <hip/hip_runtime.h>
#include <hip/hip_bf16.h>

// SubjectLayers via bf16 MFMA 32x32x16: out[b,o,t] = sum_c W[s,o,c]*x[b,c,t] + b[s,o]
// B=128, C=64, T=8192, S=16. fp32 in/out, bf16 matrix cores.
//
// R4: R3 (full-line 32x32 fragments, no LDS) +
//  - prefetch distance 2, ping-pong x buffers (covers ~900cy HBM latency;
//    full unroll keeps indices static -> no scratch)
//  - nontemporal x loads / out stores (532MB streamed once; don't thrash L2)

typedef __attribute__((ext_vector_type(8))) short  bf16x8;   // 4 VGPRs
typedef __attribute__((ext_vector_type(16))) float f32x16;   // 16 VGPRs

namespace {
constexpr int Cdim  = 64;
constexpr int Tdim  = 8192;
constexpr int NSTEP = 16;    // 32-wide t-steps per wave -> 512 t/wave
constexpr int BLOCK = 256;   // 4 waves -> 2048 t per block
}

static __device__ __forceinline__ short f2bf(float f) {
    return (short)__builtin_bit_cast(unsigned short, __float2bfloat16(f));
}

__global__ __launch_bounds__(BLOCK, 2)
void subject_layers_mfma32(const float* __restrict__ x,
                           const int*   __restrict__ subj,
                           const float* __restrict__ W,
                           const float* __restrict__ bias,
                           float*       __restrict__ out) {
    const int b    = blockIdx.y;
    const int tid  = threadIdx.x;
    const int wave = tid >> 6;
    const int lane = tid & 63;
    const int hi   = lane >> 5;   // 0..1
    const int ln   = lane & 31;   // m/n index within 32-tile
    const int s    = subj[b];

    const int t0 = (blockIdx.x * 4 + wave) * (NSTEP * 32);

    // ---- A fragments: W[s] -> bf16. 2 o-tiles (32 rows) x 4 k-blocks (16) ----
    // A[m][k]: m = ln, k = kb*16 + hi*8 + j   (mirrored with B -> k-perm cancels)
    bf16x8 afrag[2][4];
    const float* Wb = W + (size_t)s * Cdim * Cdim;
    #pragma unroll
    for (int ot = 0; ot < 2; ++ot) {
        #pragma unroll
        for (int kb = 0; kb < 4; ++kb) {
            const float* ap = Wb + (size_t)(ot * 32 + ln) * Cdim + kb * 16 + hi * 8;
            const float4 a0 = *reinterpret_cast<const float4*>(ap);
            const float4 a1 = *reinterpret_cast<const float4*>(ap + 4);
            bf16x8 f;
            f[0] = f2bf(a0.x); f[1] = f2bf(a0.y); f[2] = f2bf(a0.z); f[3] = f2bf(a0.w);
            f[4] = f2bf(a1.x); f[5] = f2bf(a1.y); f[6] = f2bf(a1.z); f[7] = f2bf(a1.w);
            afrag[ot][kb] = f;
        }
    }

    // ---- bias -> accumulator init ----
    // C/D: col = ln, row(reg r) = (r&3) + 8*(r>>2) + 4*hi   [m74/m101-verified]
    f32x16 bini[2];
    const float* bb = bias + (size_t)s * Cdim;
    #pragma unroll
    for (int ot = 0; ot < 2; ++ot)
        #pragma unroll
        for (int r = 0; r < 16; ++r)
            bini[ot][r] = bb[ot * 32 + (r & 3) + 8 * (r >> 2) + 4 * hi];

    // per-lane bases
    const float* xb = x   + (size_t)b * Cdim * Tdim + (size_t)(hi * 8) * Tdim + t0 + ln;
    float*       ob = out + (size_t)b * Cdim * Tdim + (size_t)(hi * 4) * Tdim + t0 + ln;

    // ---- main loop: 32-t steps, ping-pong buffers, prefetch distance 2 ----
    // x element for (kb,j): c = kb*16 + hi*8 + j, t = t0 + step*32 + ln
    // each load instruction: 2 rows x 128B full aligned lines.
    float xbuf[2][4][8];

    #pragma unroll
    for (int p = 0; p < 2; ++p)
        #pragma unroll
        for (int kb = 0; kb < 4; ++kb)
            #pragma unroll
            for (int j = 0; j < 8; ++j)
                xbuf[p][kb][j] =
                    __builtin_nontemporal_load(xb + (size_t)(kb * 16 + j) * Tdim + p * 32);

    #pragma unroll
    for (int step = 0; step < NSTEP; ++step) {
        constexpr int PMASK = 1;
        const int p = step & PMASK;   // compile-time after full unroll

        // consume xbuf[p] -> B fragments (compiler packs to v_cvt_pk_bf16_f32)
        bf16x8 bfrag[4];
        #pragma unroll
        for (int kb = 0; kb < 4; ++kb) {
            bf16x8 f;
            #pragma unroll
            for (int j = 0; j < 8; ++j) f[j] = f2bf(xbuf[p][kb][j]);
            bfrag[kb] = f;
        }

        // prefetch step+2 into the buffer just consumed (WAR safe: cvt issued first)
        if (step + 2 < NSTEP) {
            #pragma unroll
            for (int kb = 0; kb < 4; ++kb)
                #pragma unroll
                for (int j = 0; j < 8; ++j)
                    xbuf[p][kb][j] = __builtin_nontemporal_load(
                        xb + (size_t)(kb * 16 + j) * Tdim + (step + 2) * 32);
        }

        #pragma unroll
        for (int ot = 0; ot < 2; ++ot) {
            f32x16 acc = bini[ot];
            #pragma unroll
            for (int kb = 0; kb < 4; ++kb)
                acc = __builtin_amdgcn_mfma_f32_32x32x16_bf16(afrag[ot][kb], bfrag[kb], acc, 0, 0, 0);
            // store: per reg r, 2 rows x 128B full lines, nontemporal
            #pragma unroll
            for (int r = 0; r < 16; ++r)
                __builtin_nontemporal_store(
                    acc[r],
                    ob + (size_t)(ot * 32 + (r & 3) + 8 * (r >> 2)) * Tdim + step * 32);
        }
    }
}

extern "C" void kernel_launch(void* const* d_in, const int* in_sizes, int n_in,
                              void* d_out, int out_size, void* d_ws, size_t ws_size,
                              hipStream_t stream) {
    const float* x    = (const float*)d_in[0];   // [B, C, T]
    const int*   subj = (const int*)  d_in[1];   // [B]
    const float* W    = (const float*)d_in[2];   // [S, C, C]
    const float* bias = (const float*)d_in[3];   // [S, C]
    float*       out  = (float*)d_out;           // [B, C, T]

    const int B = in_sizes[1];                   // 128
    dim3 grid(Tdim / (4 * NSTEP * 32), B);       // (4, 128) = 512 blocks
    dim3 block(BLOCK);
    hipLaunchKernelGGL(subject_layers_mfma32, grid, block, 0, stream,
                       x, subj, W, bias, out);
}

// Round 6
// 117.444 us; speedup vs baseline: 2.7676x; 2.7676x over previous
//
#include <hip/hip_runtime.h>
#include <hip/hip_bf16.h>

// SubjectLayers via bf16 MFMA 32x32x16: out[b,o,t] = sum_c W[s,o,c]*x[b,c,t] + b[s,o]
// B=128, C=64, T=8192, S=16. fp32 in/out, bf16 matrix cores.
//
// R5 = R3 (known-good 119.8us: full-line 32x32 frags, prefetch-1, no nt)
//      + LDS epilogue so global stores are float4/lane (R1-style, measured 1.0x
//        WRITE) instead of dword scatter (measured ~2x WRITE amplification).
//  - wave-private LDS tile [64 o][32 t], row stride 36 dwords:
//      * ds_write_b32: lanes 0-31 distinct banks, half-waves 2-way (free)
//      * ds_read_b128: 16B-aligned, even quad distribution = structural 8clk
//  - no __syncthreads (wave-private region; lgkmcnt orders within wave)

typedef __attribute__((ext_vector_type(8))) short  bf16x8;   // 4 VGPRs
typedef __attribute__((ext_vector_type(16))) float f32x16;   // 16 VGPRs

namespace {
constexpr int Cdim  = 64;
constexpr int Tdim  = 8192;
constexpr int NSTEP = 16;    // 32-wide t-steps per wave -> 512 t/wave
constexpr int BLOCK = 256;   // 4 waves -> 2048 t per block
constexpr int LDSTR = 36;    // LDS row stride in dwords (pad 32->36, 16B-aligned)
}

static __device__ __forceinline__ short f2bf(float f) {
    return (short)__builtin_bit_cast(unsigned short, __float2bfloat16(f));
}

__global__ __launch_bounds__(BLOCK, 2)
void subject_layers_mfma32(const float* __restrict__ x,
                           const int*   __restrict__ subj,
                           const float* __restrict__ W,
                           const float* __restrict__ bias,
                           float*       __restrict__ out) {
    __shared__ float lds[4][Cdim * LDSTR];   // 9216B per wave, wave-private

    const int b    = blockIdx.y;
    const int tid  = threadIdx.x;
    const int wave = tid >> 6;
    const int lane = tid & 63;
    const int hi   = lane >> 5;   // 0..1
    const int ln   = lane & 31;   // m/n index within 32-tile
    const int s    = subj[b];

    const int t0 = (blockIdx.x * 4 + wave) * (NSTEP * 32);

    // ---- A fragments: W[s] -> bf16. 2 o-tiles (32 rows) x 4 k-blocks (16) ----
    // A[m][k]: m = ln, k = kb*16 + hi*8 + j   (mirrored with B -> k-perm cancels)
    bf16x8 afrag[2][4];
    const float* Wb = W + (size_t)s * Cdim * Cdim;
    #pragma unroll
    for (int ot = 0; ot < 2; ++ot) {
        #pragma unroll
        for (int kb = 0; kb < 4; ++kb) {
            const float* ap = Wb + (size_t)(ot * 32 + ln) * Cdim + kb * 16 + hi * 8;
            const float4 a0 = *reinterpret_cast<const float4*>(ap);
            const float4 a1 = *reinterpret_cast<const float4*>(ap + 4);
            bf16x8 f;
            f[0] = f2bf(a0.x); f[1] = f2bf(a0.y); f[2] = f2bf(a0.z); f[3] = f2bf(a0.w);
            f[4] = f2bf(a1.x); f[5] = f2bf(a1.y); f[6] = f2bf(a1.z); f[7] = f2bf(a1.w);
            afrag[ot][kb] = f;
        }
    }

    // ---- bias -> accumulator init ----
    // C/D: col = ln, row(reg r) = (r&3) + 8*(r>>2) + 4*hi   [m74/m101-verified]
    f32x16 bini[2];
    const float* bb = bias + (size_t)s * Cdim;
    #pragma unroll
    for (int ot = 0; ot < 2; ++ot)
        #pragma unroll
        for (int r = 0; r < 16; ++r)
            bini[ot][r] = bb[ot * 32 + (r & 3) + 8 * (r >> 2) + 4 * hi];

    // per-lane bases
    const float* xb = x + (size_t)b * Cdim * Tdim + (size_t)(hi * 8) * Tdim + t0 + ln;
    float* lw = &lds[wave][0];

    // readback/store lane mapping: lane -> (row-in-group, t4)
    const int ro = lane >> 3;        // 0..7
    const int rt = (lane & 7) * 4;   // 0,4,...,28
    float* osb = out + (size_t)b * Cdim * Tdim + t0 + rt;

    // ---- main loop: 32-t steps, 1-step x prefetch (exact R3 structure) ----
    // x element for (kb,j): c = kb*16 + hi*8 + j, t = t0 + step*32 + ln
    float xr[4][8];
    #pragma unroll
    for (int kb = 0; kb < 4; ++kb)
        #pragma unroll
        for (int j = 0; j < 8; ++j)
            xr[kb][j] = xb[(size_t)(kb * 16 + j) * Tdim];

    #pragma unroll 4
    for (int step = 0; step < NSTEP; ++step) {
        float xn[4][8];
        if (step + 1 < NSTEP) {
            #pragma unroll
            for (int kb = 0; kb < 4; ++kb)
                #pragma unroll
                for (int j = 0; j < 8; ++j)
                    xn[kb][j] = xb[(size_t)(kb * 16 + j) * Tdim + (step + 1) * 32];
        }

        // B frag: B[k][n]: n = ln, k = kb*16 + hi*8 + j  (mirror of A)
        bf16x8 bfrag[4];
        #pragma unroll
        for (int kb = 0; kb < 4; ++kb) {
            bf16x8 f;
            #pragma unroll
            for (int j = 0; j < 8; ++j) f[j] = f2bf(xr[kb][j]);
            bfrag[kb] = f;
        }

        // MFMA -> wave-private LDS tile [o][t] (stride LDSTR)
        #pragma unroll
        for (int ot = 0; ot < 2; ++ot) {
            f32x16 acc = bini[ot];
            #pragma unroll
            for (int kb = 0; kb < 4; ++kb)
                acc = __builtin_amdgcn_mfma_f32_32x32x16_bf16(afrag[ot][kb], bfrag[kb], acc, 0, 0, 0);
            #pragma unroll
            for (int r = 0; r < 16; ++r)
                lw[(ot * 32 + (r & 3) + 8 * (r >> 2) + 4 * hi) * LDSTR + ln] = acc[r];
        }

        // readback float4/lane, store 128B-per-8-lane full lines (R1-style)
        #pragma unroll
        for (int g = 0; g < 8; ++g) {
            const int o = g * 8 + ro;
            const float4 v = *reinterpret_cast<const float4*>(lw + o * LDSTR + rt);
            *reinterpret_cast<float4*>(osb + (size_t)o * Tdim + step * 32) = v;
        }

        #pragma unroll
        for (int kb = 0; kb < 4; ++kb)
            #pragma unroll
            for (int j = 0; j < 8; ++j)
                xr[kb][j] = xn[kb][j];
    }
}

extern "C" void kernel_launch(void* const* d_in, const int* in_sizes, int n_in,
                              void* d_out, int out_size, void* d_ws, size_t ws_size,
                              hipStream_t stream) {
    const float* x    = (const float*)d_in[0];   // [B, C, T]
    const int*   subj = (const int*)  d_in[1];   // [B]
    const float* W    = (const float*)d_in[2];   // [S, C, C]
    const float* bias = (const float*)d_in[3];   // [S, C]
    float*       out  = (float*)d_out;           // [B, C, T]

    const int B = in_sizes[1];                   // 128
    dim3 grid(Tdim / (4 * NSTEP * 32), B);       // (4, 128) = 512 blocks
    dim3 block(BLOCK);
    hipLaunchKernelGGL(subject_layers_mfma32, grid, block, 0, stream,
                       x, subj, W, bias, out);
}

// Round 7
// 105.295 us; speedup vs baseline: 3.0869x; 1.1154x over previous
//
#include <hip/hip_runtime.h>
#include <hip/hip_bf16.h>

// SubjectLayers via bf16 MFMA 32x32x16: out[b,o,t] = sum_c W[s,o,c]*x[b,c,t] + b[s,o]
// B=128, C=64, T=8192, S=16. fp32 in/out, bf16 matrix cores.
//
// R6: attack HBM *burst efficiency* (R3/R5 plateau ~4.4 TB/s with clean traffic).
// Every global instruction is now a 1KB single-row contiguous burst (the D2D
// copy shape that measures 6.3 TB/s), via an LDS-staged tile:
//   - block = [64 c][256 t] tile; stage x rows as 1KB/instr float4 loads
//   - B-frags from LDS (b32, conflict-free); tile buffer REUSED for output
//   - MFMA epilogue -> tile; cooperative 1KB/instr row stores
//   - 66.5KB LDS -> 2 blocks/CU; memory phase (~12.8k cyc) >> compute (~2k),
//     co-resident block covers barrier/compute gaps.

typedef __attribute__((ext_vector_type(8))) short  bf16x8;   // 4 VGPRs
typedef __attribute__((ext_vector_type(16))) float f32x16;   // 16 VGPRs

namespace {
constexpr int Cdim  = 64;
constexpr int Tdim  = 8192;
constexpr int TT    = 256;        // t per block tile
constexpr int STR   = TT + 4;     // LDS row stride in dwords (16B-aligned, de-phased banks)
constexpr int BLOCK = 256;        // 4 waves
}

static __device__ __forceinline__ short f2bf(float f) {
    return (short)__builtin_bit_cast(unsigned short, __float2bfloat16(f));
}

__global__ __launch_bounds__(BLOCK, 2)
void subject_layers_r6(const float* __restrict__ x,
                       const int*   __restrict__ subj,
                       const float* __restrict__ W,
                       const float* __restrict__ bias,
                       float*       __restrict__ out) {
    __shared__ float tile[Cdim * STR];   // 66560 B, x-tile then reused as out-tile

    const int b    = blockIdx.y;
    const int tb   = blockIdx.x;
    const int tid  = threadIdx.x;
    const int wave = tid >> 6;
    const int lane = tid & 63;
    const int hi   = lane >> 5;   // 0..1
    const int ln   = lane & 31;   // m/n index within 32-tile
    const int s    = subj[b];

    const size_t xbase = (size_t)b * Cdim * Tdim + (size_t)tb * TT;

    // ---- stage x tile: wave w handles rows g*4+w; one instr = one row = 1KB ----
    {
        float4 v[4];
        #pragma unroll
        for (int gg = 0; gg < 4; ++gg) {   // groups of 4 rows: load 4, then write 4
            #pragma unroll
            for (int g = 0; g < 4; ++g) {
                const int row = (gg * 4 + g) * 4 + wave;
                v[g] = *reinterpret_cast<const float4*>(x + xbase + (size_t)row * Tdim + lane * 4);
            }
            #pragma unroll
            for (int g = 0; g < 4; ++g) {
                const int row = (gg * 4 + g) * 4 + wave;
                *reinterpret_cast<float4*>(&tile[row * STR + lane * 4]) = v[g];
            }
        }
    }

    // ---- A fragments: W[s] -> bf16 (overlaps staging; no dependency) ----
    // A[m][k]: m = ln, k = kb*16 + hi*8 + j  (mirrored with B -> k-perm cancels)
    bf16x8 afrag[2][4];
    const float* Wb = W + (size_t)s * Cdim * Cdim;
    #pragma unroll
    for (int ot = 0; ot < 2; ++ot) {
        #pragma unroll
        for (int kb = 0; kb < 4; ++kb) {
            const float* ap = Wb + (size_t)(ot * 32 + ln) * Cdim + kb * 16 + hi * 8;
            const float4 a0 = *reinterpret_cast<const float4*>(ap);
            const float4 a1 = *reinterpret_cast<const float4*>(ap + 4);
            bf16x8 f;
            f[0] = f2bf(a0.x); f[1] = f2bf(a0.y); f[2] = f2bf(a0.z); f[3] = f2bf(a0.w);
            f[4] = f2bf(a1.x); f[5] = f2bf(a1.y); f[6] = f2bf(a1.z); f[7] = f2bf(a1.w);
            afrag[ot][kb] = f;
        }
    }

    // ---- bias -> accumulator init ----
    // C/D: col = ln, row(reg r) = (r&3) + 8*(r>>2) + 4*hi   [m74/m101-verified]
    f32x16 bini[2];
    const float* bb = bias + (size_t)s * Cdim;
    #pragma unroll
    for (int ot = 0; ot < 2; ++ot)
        #pragma unroll
        for (int r = 0; r < 16; ++r)
            bini[ot][r] = bb[ot * 32 + (r & 3) + 8 * (r >> 2) + 4 * hi];

    __syncthreads();   // x tile ready

    // ---- B fragments for this wave's two 32-t steps (then tile is dead) ----
    // B[k][n]: n = ln, k = kb*16 + hi*8 + j ; col = wave*64 + st*32 + ln
    bf16x8 bfrag[2][4];
    #pragma unroll
    for (int st = 0; st < 2; ++st) {
        const int col = wave * 64 + st * 32 + ln;
        #pragma unroll
        for (int kb = 0; kb < 4; ++kb) {
            bf16x8 f;
            #pragma unroll
            for (int j = 0; j < 8; ++j)
                f[j] = f2bf(tile[(kb * 16 + hi * 8 + j) * STR + col]);
            bfrag[st][kb] = f;
        }
    }

    __syncthreads();   // all reads done; tile now the out-tile

    // ---- MFMA + epilogue into tile[o][col] ----
    #pragma unroll
    for (int st = 0; st < 2; ++st) {
        const int col = wave * 64 + st * 32 + ln;
        #pragma unroll
        for (int ot = 0; ot < 2; ++ot) {
            f32x16 acc = bini[ot];
            #pragma unroll
            for (int kb = 0; kb < 4; ++kb)
                acc = __builtin_amdgcn_mfma_f32_32x32x16_bf16(afrag[ot][kb], bfrag[st][kb], acc, 0, 0, 0);
            #pragma unroll
            for (int r = 0; r < 16; ++r)
                tile[(ot * 32 + (r & 3) + 8 * (r >> 2) + 4 * hi) * STR + col] = acc[r];
        }
    }

    __syncthreads();   // out tile complete

    // ---- cooperative store: same 1KB-row shape as the load ----
    #pragma unroll
    for (int g = 0; g < 16; ++g) {
        const int row = g * 4 + wave;
        const float4 v = *reinterpret_cast<const float4*>(&tile[row * STR + lane * 4]);
        *reinterpret_cast<float4*>(out + xbase + (size_t)row * Tdim + lane * 4) = v;
    }
}

extern "C" void kernel_launch(void* const* d_in, const int* in_sizes, int n_in,
                              void* d_out, int out_size, void* d_ws, size_t ws_size,
                              hipStream_t stream) {
    const float* x    = (const float*)d_in[0];   // [B, C, T]
    const int*   subj = (const int*)  d_in[1];   // [B]
    const float* W    = (const float*)d_in[2];   // [S, C, C]
    const float* bias = (const float*)d_in[3];   // [S, C]
    float*       out  = (float*)d_out;           // [B, C, T]

    const int B = in_sizes[1];                   // 128
    dim3 grid(Tdim / TT, B);                     // (32, 128) = 4096 blocks
    dim3 block(BLOCK);
    hipLaunchKernelGGL(subject_layers_r6, grid, block, 0, stream,
                       x, subj, W, bias, out);
}